// Round 14
// baseline (129.725 us; speedup 1.0000x reference)
//
#include <hip/hip_runtime.h>

// Armor: strict IEEE semantics regardless of harness flags (validated R10-R13).
#pragma float_control(precise, on)

__device__ __forceinline__ float readlane_f(float v, int k) {
    return __uint_as_float((unsigned)__builtin_amdgcn_readlane((int)__float_as_uint(v), k));
}

extern "C" __global__ void __launch_bounds__(256)
jpeg_compress(const float* __restrict__ image,
              const float* __restrict__ matrix,
              const float* __restrict__ shiftv,
              const float* __restrict__ y_table,
              const float* __restrict__ c_table,
              const float* __restrict__ dct_tensor,
              const float* __restrict__ dct_scale,
              const int*   __restrict__ factor,
              float* __restrict__ out)
{
    const int t    = threadIdx.x;
    const int lane = t & 63;
    const int wave = t >> 6;
    const int wg   = blockIdx.x;
    const int img  = wg >> 10;
    const int tile = wg & 1023;
    const int ty   = tile >> 5;
    const int tx   = tile & 31;

    __shared__ __align__(16) float ylds[16 * 64];   // 16 Y blocks, block-major
    __shared__ __align__(16) float clds[8 * 64];    // 4 Cb blocks then 4 Cr blocks

    // ---- per-lane constants ----
    float wcol[64];
    #pragma unroll
    for (int k = 0; k < 64; ++k) wcol[k] = dct_tensor[k * 64 + lane];
    const float scale_l = dct_scale[lane];
    const float fac = (float)factor[0];
    const float qy = y_table[lane] * fac;   // factor==1 -> exact
    const float qc = c_table[lane] * fac;
    // VALIDATED (R13, output 0): quantize is reciprocal-multiply, f32:
    // round(d * RN(1/q)), half-even
    const float rqy = 1.0f / qy;
    const float rqc = 1.0f / qc;

    const float m00 = matrix[0], m01 = matrix[1], m02 = matrix[2];
    const float m10 = matrix[3], m11 = matrix[4], m12 = matrix[5];
    const float m20 = matrix[6], m21 = matrix[7], m22 = matrix[8];
    const float s0 = shiftv[0], s1 = shiftv[1], s2 = shiftv[2];

    // ---- phase 1: load 32x32 RGB tile, YCbCr, pool chroma, stage to LDS ----
    const int row = t >> 3;            // 0..31
    const int c0  = (t & 7) << 2;      // 0..28 step 4
    const float* p = image + (size_t)img * 3145728u
                   + (size_t)(ty * 32 + row) * 1024 + (size_t)(tx * 32 + c0);
    float4 R4 = *(const float4*)p;
    float4 G4 = *(const float4*)(p + 1048576);
    float4 B4 = *(const float4*)(p + 2097152);

    float yv[4], cbv[4], crv[4];
    {
        #pragma clang fp contract(off)
        float Rr[4] = {R4.x, R4.y, R4.z, R4.w};
        float Gg[4] = {G4.x, G4.y, G4.z, G4.w};
        float Bb[4] = {B4.x, B4.y, B4.z, B4.w};
        #pragma unroll
        for (int j = 0; j < 4; ++j) {
            float R = Rr[j] * 255.0f, G = Gg[j] * 255.0f, B = Bb[j] * 255.0f;
            // VALIDATED (R13): einsum = sequential c, mul then add (no fma),
            // then + shift as separate rounded add
            yv[j]  = (((R * m00 + G * m10) + B * m20) + s0) - 128.0f;
            cbv[j] =  ((R * m01 + G * m11) + B * m21) + s1;
            crv[j] =  ((R * m02 + G * m12) + B * m22) + s2;
        }
    }

    {
        const int yblk = ((row >> 3) << 2) + (c0 >> 3);
        const int yk   = ((row & 7) << 3) + (c0 & 7);
        *(float4*)&ylds[yblk * 64 + yk] = make_float4(yv[0], yv[1], yv[2], yv[3]);
    }

    float bcb[4], bcr[4];
    #pragma unroll
    for (int j = 0; j < 4; ++j) {
        bcb[j] = __shfl_down(cbv[j], 8, 64);
        bcr[j] = __shfl_down(crv[j], 8, 64);
    }
    if ((row & 1) == 0) {
        #pragma clang fp contract(off)
        // NEW: pairwise pool association (reduce axis-4 first, then axis-2):
        // (x00 + x01) + (x10 + x11), then exact /4, then -128
        float p0cb = (((cbv[0] + cbv[1]) + (bcb[0] + bcb[1])) / 4.0f) - 128.0f;
        float p1cb = (((cbv[2] + cbv[3]) + (bcb[2] + bcb[3])) / 4.0f) - 128.0f;
        float p0cr = (((crv[0] + crv[1]) + (bcr[0] + bcr[1])) / 4.0f) - 128.0f;
        float p1cr = (((crv[2] + crv[3]) + (bcr[2] + bcr[3])) / 4.0f) - 128.0f;
        const int pr = row >> 1;           // 0..15
        const int pc = (t & 7) << 1;       // 0..14 step 2
        const int cblk = ((pr >> 3) << 1) + (pc >> 3);
        const int kk = ((pr & 7) << 3) + (pc & 7);
        clds[cblk * 64 + kk]           = p0cb;
        clds[cblk * 64 + kk + 1]       = p1cb;
        clds[(4 + cblk) * 64 + kk]     = p0cr;
        clds[(4 + cblk) * 64 + kk + 1] = p1cr;
    }
    __syncthreads();

    // ---- phase 2: per-wave DCT + quantize of 6 blocks ----
    #pragma unroll
    for (int i = 0; i < 6; ++i) {
        const int blk = wave * 6 + i;      // 0..23
        const float* src;
        float rqt;
        size_t obase;
        if (blk < 16) {
            src = &ylds[blk * 64];
            rqt = rqy;
            const int gbr = ty * 4 + (blk >> 2);
            const int gbc = tx * 4 + (blk & 3);
            obase = ((size_t)img * 16384 + (size_t)(gbr * 128 + gbc)) * 64;
        } else {
            const int cb = blk - 16;       // 0..7: 0-3 Cb, 4-7 Cr
            src = &clds[cb * 64];
            rqt = rqc;
            const int cc = cb & 3;
            const int gbr = ty * 2 + (cc >> 1);
            const int gbc = tx * 2 + (cc & 1);
            obase = (size_t)16777216u + (size_t)(cb >> 2) * 4194304u
                  + ((size_t)img * 4096 + (size_t)(gbr * 64 + gbc)) * 64;
        }
        const float rb = src[lane];        // lane l holds b[l]; wave-uniform vector
        float acc = 0.0f;
        // VALIDATED (R13): flat 64-term dot, k ascending, single accumulator, FMA
        #pragma unroll
        for (int k = 0; k < 64; ++k)
            acc = fmaf(readlane_f(rb, k), wcol[k], acc);
        const float d = scale_l * acc;     // f32
        {
            #pragma clang fp contract(off)
            // VALIDATED (R13): reciprocal-multiply quantize, f32 half-even round
            out[obase + lane] = rintf(d * rqt);
        }
    }
}

extern "C" void kernel_launch(void* const* d_in, const int* in_sizes, int n_in,
                              void* d_out, int out_size, void* d_ws, size_t ws_size,
                              hipStream_t stream)
{
    const float* image   = (const float*)d_in[0];
    const float* matrix  = (const float*)d_in[1];
    const float* shiftv  = (const float*)d_in[2];
    const float* y_table = (const float*)d_in[3];
    const float* c_table = (const float*)d_in[4];
    const float* dct_t   = (const float*)d_in[5];
    const float* dct_s   = (const float*)d_in[6];
    const int*   factor  = (const int*)d_in[7];
    jpeg_compress<<<dim3(16384), dim3(256), 0, stream>>>(
        image, matrix, shiftv, y_table, c_table, dct_t, dct_s, factor,
        (float*)d_out);
}